// Round 1
// baseline (1301.208 us; speedup 1.0000x reference)
//
#include <hip/hip_runtime.h>
#include <math.h>

#define T_TOK 32768
#define DM 512
#define DFF 2048
#define NE 8
#define BM 64
#define FFC 128
#define NCH (DFF / FFC)   // 16 chunks

typedef __attribute__((ext_vector_type(8))) short short8;
typedef __attribute__((ext_vector_type(4))) float f32x4;

__device__ __forceinline__ unsigned int f2bf1(float f) {
  union { float f; unsigned int u; } x; x.f = f;
  return (x.u + 0x7fffu + ((x.u >> 16) & 1u)) >> 16;  // RNE, low 16 bits valid
}

// transpose + convert: src [E][R][C] f32 -> dst [E][C][R] bf16
__global__ void tcvt_kernel(const float* __restrict__ src, unsigned short* __restrict__ dst,
                            int R, int C) {
  __shared__ float tile[32][33];
  int e = blockIdx.z;
  const float* s = src + (size_t)e * R * C;
  unsigned short* d = dst + (size_t)e * R * C;
  int c0 = blockIdx.x * 32, r0 = blockIdx.y * 32;
  int tx = threadIdx.x, ty = threadIdx.y;
#pragma unroll
  for (int i = 0; i < 4; ++i)
    tile[ty + i * 8][tx] = s[(size_t)(r0 + ty + i * 8) * C + c0 + tx];
  __syncthreads();
#pragma unroll
  for (int i = 0; i < 4; ++i)
    d[(size_t)(c0 + ty + i * 8) * R + r0 + tx] = (unsigned short)f2bf1(tile[tx][ty + i * 8]);
}

// gating: 16 tokens per 1024-thread block (wave per token), block-aggregated bucket append
__global__ __launch_bounds__(1024) void gate_kernel(
    const float* __restrict__ x, const float* __restrict__ gw,
    int* __restrict__ cnt, int* __restrict__ tok, float* __restrict__ wgt) {
  __shared__ int lcnt[NE];
  __shared__ int lbase[NE];
  __shared__ int wslot[16][2];
  int tid = threadIdx.x;
  int wid = tid >> 6, lane = tid & 63;
  int t = blockIdx.x * 16 + wid;
  if (tid < NE) lcnt[tid] = 0;
  __syncthreads();

  float acc[NE];
#pragma unroll
  for (int e = 0; e < NE; ++e) acc[e] = 0.f;
  const float* xr = x + (size_t)t * DM;
#pragma unroll
  for (int j = 0; j < 8; ++j) {
    int dI = j * 64 + lane;
    float xv = xr[dI];
    const float* g = gw + dI * NE;
#pragma unroll
    for (int e = 0; e < NE; ++e) acc[e] = fmaf(xv, g[e], acc[e]);
  }
#pragma unroll
  for (int off = 32; off >= 1; off >>= 1) {
#pragma unroll
    for (int e = 0; e < NE; ++e) acc[e] += __shfl_xor(acc[e], off);
  }

  int e0 = 0, e1 = 0; float w0 = 0.f, w1v = 0.f;
  if (lane == 0) {
    float l0 = acc[0];
#pragma unroll
    for (int e = 1; e < NE; ++e) if (acc[e] > l0) { l0 = acc[e]; e0 = e; }
    e1 = (e0 == 0) ? 1 : 0; float l1 = acc[e1];
#pragma unroll
    for (int e = 0; e < NE; ++e) if (e != e0 && acc[e] > l1) { l1 = acc[e]; e1 = e; }
    w0 = 1.f / (1.f + expf(l1 - l0));   // = p0/(p0+p1), exact renormalized top-2
    w1v = 1.f - w0;
    wslot[wid][0] = atomicAdd(&lcnt[e0], 1);
    wslot[wid][1] = atomicAdd(&lcnt[e1], 1);
  }
  __syncthreads();
  if (tid < NE) lbase[tid] = atomicAdd(&cnt[tid * 64], lcnt[tid]);
  __syncthreads();
  if (lane == 0) {
    int p0 = lbase[e0] + wslot[wid][0];
    tok[e0 * T_TOK + p0] = t; wgt[e0 * T_TOK + p0] = w0;
    int p1 = lbase[e1] + wslot[wid][1];
    tok[e1 * T_TOK + p1] = t; wgt[e1 * T_TOK + p1] = w1v;
  }
}

// fused FFN: per (expert, 64-token tile): y = gelu(X@W1+b1)@W2+b2, scaled atomic scatter
__global__ __launch_bounds__(512, 4) void ffn_kernel(
    const float* __restrict__ x,
    const unsigned short* __restrict__ w1t,   // [E][DFF][DM] bf16
    const float* __restrict__ b1,             // [E][DFF]
    const unsigned short* __restrict__ w2t,   // [E][DM][DFF] bf16
    const float* __restrict__ b2,             // [E][DM]
    const int* __restrict__ cnt,
    const int* __restrict__ tok,
    const float* __restrict__ wgt,
    float* __restrict__ out) {
  int e = (int)blockIdx.x & 7;                // expert == XCD (round-robin dispatch)
  int tile = (int)blockIdx.x >> 3;
  int ce = cnt[e * 64];
  int m0 = tile * BM;
  if (m0 >= ce) return;

  __shared__ unsigned short Xs[BM * DM];    // 64KB, row pitch 1024B, XOR swizzle
  __shared__ unsigned short Hs[BM * FFC];   // 16KB, row pitch 256B, XOR swizzle

  int tid = (int)threadIdx.x;
  int lane = tid & 63;
  int wid = tid >> 6;
  const int* tokg = tok + e * T_TOK + m0;
  const float* wgtg = wgt + e * T_TOK + m0;

  // stage X tile (gathered rows) f32 -> bf16 LDS
#pragma unroll
  for (int it = 0; it < 16; ++it) {
    int i = tid + it * 512;
    int r = i >> 7, c = i & 127;
    int tk = (m0 + r < ce) ? tokg[r] : 0;
    f32x4 xv = *(const f32x4*)(x + (size_t)tk * DM + c * 4);
    unsigned int lo = f2bf1(xv[0]) | (f2bf1(xv[1]) << 16);
    unsigned int hi = f2bf1(xv[2]) | (f2bf1(xv[3]) << 16);
    int byteoff = r * 1024 + ((c * 8) ^ ((r & 7) << 4));
    *(uint2*)((char*)Xs + byteoff) = make_uint2(lo, hi);
  }

  int wn = wid;              // GEMM2: wave's 64-col slice of y[64][512]
  int wm = wid & 1, wf = wid >> 1;  // GEMM1: wave = [32m x 32f] slice of h[64][128]
  int fl = lane & 15;
  int kb = (lane >> 4) << 3;
  int sw = (fl & 7) << 4;

  float b2v[4];
#pragma unroll
  for (int nf = 0; nf < 4; ++nf) b2v[nf] = b2[e * DM + wn * 64 + nf * 16 + fl];

  f32x4 yacc[4][4];
#pragma unroll
  for (int a = 0; a < 4; ++a)
#pragma unroll
    for (int b = 0; b < 4; ++b) yacc[a][b] = (f32x4){0.f, 0.f, 0.f, 0.f};

  for (int cc = 0; cc < NCH; ++cc) {
    __syncthreads();  // prev GEMM2 done reading Hs (and X staging visible at cc=0)

    // ---- GEMM1: h[64][128] chunk = X @ W1[:, chunk] ----
    const unsigned short* w1base = w1t + (size_t)(e * DFF + cc * FFC + wf * 32) * DM;
    f32x4 hacc[2][2];
#pragma unroll
    for (int a = 0; a < 2; ++a)
#pragma unroll
      for (int b = 0; b < 2; ++b) hacc[a][b] = (f32x4){0.f, 0.f, 0.f, 0.f};
#pragma unroll 4
    for (int ks = 0; ks < 16; ++ks) {
      int k = ks * 32 + kb;
      short8 bf0 = *(const short8*)(w1base + (size_t)fl * DM + k);
      short8 bf1 = *(const short8*)(w1base + (size_t)(16 + fl) * DM + k);
      short8 a0 = *(const short8*)((const char*)Xs + ((wm * 32 + fl) * 1024 + ((k * 2) ^ sw)));
      short8 a1 = *(const short8*)((const char*)Xs + ((wm * 32 + 16 + fl) * 1024 + ((k * 2) ^ sw)));
      hacc[0][0] = __builtin_amdgcn_mfma_f32_16x16x32_bf16(a0, bf0, hacc[0][0], 0, 0, 0);
      hacc[0][1] = __builtin_amdgcn_mfma_f32_16x16x32_bf16(a0, bf1, hacc[0][1], 0, 0, 0);
      hacc[1][0] = __builtin_amdgcn_mfma_f32_16x16x32_bf16(a1, bf0, hacc[1][0], 0, 0, 0);
      hacc[1][1] = __builtin_amdgcn_mfma_f32_16x16x32_bf16(a1, bf1, hacc[1][1], 0, 0, 0);
    }

    // bias + exact gelu -> Hs (bf16)
    float b1v0 = b1[e * DFF + cc * FFC + wf * 32 + fl];
    float b1v1 = b1[e * DFF + cc * FFC + wf * 32 + 16 + fl];
#pragma unroll
    for (int mf = 0; mf < 2; ++mf)
#pragma unroll
      for (int nf = 0; nf < 2; ++nf)
#pragma unroll
        for (int j = 0; j < 4; ++j) {
          int m = wm * 32 + mf * 16 + ((lane >> 4) << 2) + j;
          int f = wf * 32 + nf * 16 + fl;
          float v = hacc[mf][nf][j] + (nf ? b1v1 : b1v0);
          v = 0.5f * v * (1.f + erff(v * 0.70710678118654752f));
          *(unsigned short*)((char*)Hs + (m * 256 + ((f * 2) ^ ((m & 7) << 4)))) =
              (unsigned short)f2bf1(v);
        }
    __syncthreads();  // Hs ready

    // ---- GEMM2: y[64][512] += gelu_chunk @ W2[chunk, :] ----
    const unsigned short* w2base = w2t + (size_t)(e * DM + wn * 64) * DFF + cc * FFC;
#pragma unroll
    for (int ks = 0; ks < 4; ++ks) {
      int k = ks * 32 + kb;
      short8 af[4];
#pragma unroll
      for (int mf = 0; mf < 4; ++mf) {
        int m = mf * 16 + fl;
        af[mf] = *(const short8*)((const char*)Hs + (m * 256 + ((k * 2) ^ sw)));
      }
#pragma unroll
      for (int nf = 0; nf < 4; ++nf) {
        short8 bfr = *(const short8*)(w2base + (size_t)(nf * 16 + fl) * DFF + k);
#pragma unroll
        for (int mf = 0; mf < 4; ++mf)
          yacc[mf][nf] = __builtin_amdgcn_mfma_f32_16x16x32_bf16(af[mf], bfr, yacc[mf][nf], 0, 0, 0);
      }
    }
  }

  // epilogue: out[tok[m]] += w[m] * (y + b2)
#pragma unroll
  for (int mf = 0; mf < 4; ++mf)
#pragma unroll
    for (int j = 0; j < 4; ++j) {
      int m = mf * 16 + ((lane >> 4) << 2) + j;
      if (m0 + m < ce) {
        int tk = tokg[m];
        float w = wgtg[m];
        float* orow = out + (size_t)tk * DM;
#pragma unroll
        for (int nf = 0; nf < 4; ++nf) {
          int n = wn * 64 + nf * 16 + fl;
          atomicAdd(orow + n, w * (yacc[mf][nf][j] + b2v[nf]));
        }
      }
    }
}

extern "C" void kernel_launch(void* const* d_in, const int* in_sizes, int n_in,
                              void* d_out, int out_size, void* d_ws, size_t ws_size,
                              hipStream_t stream) {
  (void)in_sizes; (void)n_in; (void)out_size; (void)ws_size;
  const float* x  = (const float*)d_in[0];
  const float* gw = (const float*)d_in[1];
  const float* w1 = (const float*)d_in[2];
  const float* b1 = (const float*)d_in[3];
  const float* w2 = (const float*)d_in[4];
  const float* b2 = (const float*)d_in[5];
  float* out = (float*)d_out;

  // ws layout (~34.6 MB): cnt (padded 256B/expert) | tok | wgt | w1t bf16 | w2t bf16
  char* ws = (char*)d_ws;
  int*   cnt = (int*)ws;
  int*   tok = (int*)(ws + 4096);
  float* wgt = (float*)(ws + 4096 + 1048576);
  unsigned short* w1t = (unsigned short*)(ws + 4096 + 2097152);
  unsigned short* w2t = (unsigned short*)(ws + 4096 + 2097152 + 16777216);

  hipMemsetAsync(cnt, 0, 4096, stream);
  hipMemsetAsync(out, 0, (size_t)T_TOK * DM * sizeof(float), stream);
  tcvt_kernel<<<dim3(DFF / 32, DM / 32, NE), dim3(32, 8), 0, stream>>>(w1, w1t, DM, DFF);
  tcvt_kernel<<<dim3(DM / 32, DFF / 32, NE), dim3(32, 8), 0, stream>>>(w2, w2t, DFF, DM);
  gate_kernel<<<T_TOK / 16, 1024, 0, stream>>>(x, gw, cnt, tok, wgt);
  ffn_kernel<<<NE * (T_TOK / BM), 512, 0, stream>>>(x, w1t, b1, w2t, b2, cnt, tok, wgt, out);
}

// Round 2
// 805.876 us; speedup vs baseline: 1.6146x; 1.6146x over previous
//
#include <hip/hip_runtime.h>
#include <math.h>

#define T_TOK 32768
#define DM 512
#define DFF 2048
#define NE 8
#define BM 64
#define FFC 256
#define NCH (DFF / FFC)   // 8 chunks

typedef __attribute__((ext_vector_type(8))) short short8;
typedef __attribute__((ext_vector_type(4))) float f32x4;

__device__ __forceinline__ unsigned int f2bf1(float f) {
  union { float f; unsigned int u; } x; x.f = f;
  return (x.u + 0x7fffu + ((x.u >> 16) & 1u)) >> 16;  // RNE
}
__device__ __forceinline__ float bf2f(unsigned int b) {
  union { unsigned int u; float f; } x; x.u = b << 16; return x.f;
}

// transpose + convert: src [E][R][C] f32 -> dst [E][C][R] bf16
__global__ void tcvt_kernel(const float* __restrict__ src, unsigned short* __restrict__ dst,
                            int R, int C) {
  __shared__ float tile[32][33];
  int e = blockIdx.z;
  const float* s = src + (size_t)e * R * C;
  unsigned short* d = dst + (size_t)e * R * C;
  int c0 = blockIdx.x * 32, r0 = blockIdx.y * 32;
  int tx = threadIdx.x, ty = threadIdx.y;
#pragma unroll
  for (int i = 0; i < 4; ++i)
    tile[ty + i * 8][tx] = s[(size_t)(r0 + ty + i * 8) * C + c0 + tx];
  __syncthreads();
#pragma unroll
  for (int i = 0; i < 4; ++i)
    d[(size_t)(c0 + ty + i * 8) * R + r0 + tx] = (unsigned short)f2bf1(tile[tx][ty + i * 8]);
}

// gating: 16 tokens per block (wave/token); also emits x as bf16 and token->slot maps
__global__ __launch_bounds__(1024) void gate_kernel(
    const float* __restrict__ x, const float* __restrict__ gw,
    int* __restrict__ cnt, int* __restrict__ tok, float* __restrict__ wgt,
    unsigned int* __restrict__ xb,
    int2* __restrict__ se2, int2* __restrict__ sp2, float2* __restrict__ sw2) {
  __shared__ int lcnt[NE];
  __shared__ int lbase[NE];
  __shared__ int wslot[16][2];
  __shared__ int winfo[16][2];
  __shared__ float wval[16][2];
  int tid = threadIdx.x;
  int wid = tid >> 6, lane = tid & 63;
  int t = blockIdx.x * 16 + wid;
  if (tid < NE) lcnt[tid] = 0;
  __syncthreads();

  float acc[NE];
#pragma unroll
  for (int e = 0; e < NE; ++e) acc[e] = 0.f;
  const float* xr = x + (size_t)t * DM;
  unsigned int* xbr = xb + (size_t)t * (DM / 2);
#pragma unroll
  for (int j = 0; j < 4; ++j) {
    int d0 = j * 128 + lane * 2;
    float2 xv = *(const float2*)(xr + d0);
    const float* g0 = gw + d0 * NE;
#pragma unroll
    for (int e = 0; e < NE; ++e) acc[e] += xv.x * g0[e] + xv.y * g0[NE + e];
    xbr[j * 64 + lane] = f2bf1(xv.x) | (f2bf1(xv.y) << 16);
  }
#pragma unroll
  for (int off = 32; off >= 1; off >>= 1) {
#pragma unroll
    for (int e = 0; e < NE; ++e) acc[e] += __shfl_xor(acc[e], off);
  }
  if (lane == 0) {
    int e0 = 0; float l0 = acc[0];
#pragma unroll
    for (int e = 1; e < NE; ++e) if (acc[e] > l0) { l0 = acc[e]; e0 = e; }
    int e1 = (e0 == 0) ? 1 : 0; float l1 = acc[e1];
#pragma unroll
    for (int e = 0; e < NE; ++e) if (e != e0 && acc[e] > l1) { l1 = acc[e]; e1 = e; }
    float w0 = 1.f / (1.f + expf(l1 - l0));   // renormalized top-2, exact
    winfo[wid][0] = e0; winfo[wid][1] = e1;
    wval[wid][0] = w0;  wval[wid][1] = 1.f - w0;
    wslot[wid][0] = atomicAdd(&lcnt[e0], 1);
    wslot[wid][1] = atomicAdd(&lcnt[e1], 1);
  }
  __syncthreads();
  if (tid < NE) lbase[tid] = atomicAdd(&cnt[tid * 64], lcnt[tid]);
  __syncthreads();
  if (lane == 0) {
    int e0 = winfo[wid][0], e1 = winfo[wid][1];
    int p0 = lbase[e0] + wslot[wid][0];
    int p1 = lbase[e1] + wslot[wid][1];
    tok[e0 * T_TOK + p0] = t; wgt[e0 * T_TOK + p0] = wval[wid][0];
    tok[e1 * T_TOK + p1] = t; wgt[e1 * T_TOK + p1] = wval[wid][1];
    se2[t] = make_int2(e0, e1);
    sp2[t] = make_int2(p0, p1);
    sw2[t] = make_float2(wval[wid][0], wval[wid][1]);
  }
}

// fused FFN: (expert, 64-token tile); 16 waves; W1/W2 read once per block,
// register-ring prefetched; Hs double-buffered (1 barrier/chunk).
template <int USE_Y>
__global__ __launch_bounds__(1024) void ffn_kernel(
    const unsigned int* __restrict__ xb,       // x as bf16 pairs [T][256] u32
    const unsigned short* __restrict__ w1t,    // [E][DFF][DM] bf16
    const float* __restrict__ b1,
    const unsigned short* __restrict__ w2t,    // [E][DM][DFF] bf16
    const float* __restrict__ b2,
    const int* __restrict__ cnt,
    const int* __restrict__ tok,
    const float* __restrict__ wgt,
    unsigned int* __restrict__ ypair,          // bf16 row-pair packed [rows/2][DM] u32
    float* __restrict__ out) {
  int e = (int)blockIdx.x & 7;                 // expert <-> XCD affinity
  int tile = (int)blockIdx.x >> 3;
  int ce = cnt[e * 64];
  int m0 = tile * BM;
  if (m0 >= ce) return;

  __shared__ unsigned short Xs[BM * DM];       // 64 KB, linear rows, source-swizzled
  __shared__ unsigned short Hs[2][BM * FFC];   // 2 x 32 KB

  int tid = (int)threadIdx.x;
  int lane = tid & 63;
  int wid = tid >> 6;        // 0..15
  int fl = lane & 15;
  int q = lane >> 4;
  int sw = (fl & 7) << 4;

  const int* tokg = tok + e * T_TOK + m0;

  // stage Xs via global_load_lds; swizzle applied on the per-lane GLOBAL source
#pragma unroll
  for (int i = 0; i < 4; ++i) {
    int r = i * 16 + wid;                      // one row per wave per round
    int tk = (m0 + r < ce) ? tokg[r] : tokg[0];
    const char* src = (const char*)(xb + (size_t)tk * (DM / 2)) + ((lane * 16) ^ ((r & 7) * 16));
    __builtin_amdgcn_global_load_lds(
        (const __attribute__((address_space(1))) unsigned int*)src,
        (__attribute__((address_space(3))) unsigned int*)(Xs + r * DM),
        16, 0, 0);
  }
  __syncthreads();

  f32x4 yacc[4][2];
#pragma unroll
  for (int a = 0; a < 4; ++a) {
    yacc[a][0] = (f32x4){0.f, 0.f, 0.f, 0.f};
    yacc[a][1] = (f32x4){0.f, 0.f, 0.f, 0.f};
  }

  const char* w1p = (const char*)(w1t + ((size_t)e * DFF + wid * 16 + fl) * DM) + q * 16;
  const char* w2p0 = (const char*)(w2t + ((size_t)e * DM + wid * 32 + fl) * DFF) + q * 16;
  const char* w2p1 = w2p0 + (size_t)16 * DFF * 2;

  for (int cc = 0; cc < NCH; ++cc) {
    // ---- GEMM1: h[64][256-chunk]; wave owns 16 f-cols; depth-4 load ring ----
    const char* wb = w1p + (size_t)cc * FFC * DM * 2;
    short8 wreg[4];
    wreg[0] = *(const short8*)(wb);
    wreg[1] = *(const short8*)(wb + 64);
    wreg[2] = *(const short8*)(wb + 128);
    wreg[3] = *(const short8*)(wb + 192);
    f32x4 hacc[4];
#pragma unroll
    for (int a = 0; a < 4; ++a) hacc[a] = (f32x4){0.f, 0.f, 0.f, 0.f};
#pragma unroll
    for (int ks = 0; ks < 16; ++ks) {
      short8 wc = wreg[ks & 3];
      if (ks + 4 < 16) wreg[ks & 3] = *(const short8*)(wb + (ks + 4) * 64);
#pragma unroll
      for (int mt = 0; mt < 4; ++mt) {
        short8 a = *(const short8*)((const char*)Xs +
                     ((mt * 16 + fl) * 1024 + ((ks * 64 + q * 16) ^ sw)));
        hacc[mt] = __builtin_amdgcn_mfma_f32_16x16x32_bf16(a, wc, hacc[mt], 0, 0, 0);
      }
    }

    // bias + exact gelu -> Hs[cc&1]
    float bv = b1[e * DFF + cc * FFC + wid * 16 + fl];
    unsigned short* hs = Hs[cc & 1];
    {
      int f = wid * 16 + fl;
#pragma unroll
      for (int mt = 0; mt < 4; ++mt)
#pragma unroll
        for (int j = 0; j < 4; ++j) {
          int m = mt * 16 + q * 4 + j;
          float v = hacc[mt][j] + bv;
          v = 0.5f * v * (1.f + erff(v * 0.70710678118654752f));
          *(unsigned short*)((char*)hs + (m * 512 + ((f * 2) ^ ((m & 7) << 4)))) =
              (unsigned short)f2bf1(v);
        }
    }
    __syncthreads();   // the single barrier per chunk: Hs[cc&1] ready

    // ---- GEMM2: y[64][512] += gelu_chunk @ W2[chunk,:]; wave owns 32 n-cols ----
    const char* wc0 = w2p0 + cc * 512;
    const char* wc1 = w2p1 + cc * 512;
    short8 v0[2], v1[2];
    v0[0] = *(const short8*)(wc0);      v1[0] = *(const short8*)(wc1);
    v0[1] = *(const short8*)(wc0 + 64); v1[1] = *(const short8*)(wc1 + 64);
#pragma unroll
    for (int ks = 0; ks < 8; ++ks) {
      short8 b0 = v0[ks & 1], b1v = v1[ks & 1];
      if (ks + 2 < 8) {
        v0[ks & 1] = *(const short8*)(wc0 + (ks + 2) * 64);
        v1[ks & 1] = *(const short8*)(wc1 + (ks + 2) * 64);
      }
      short8 af[4];
#pragma unroll
      for (int mf = 0; mf < 4; ++mf)
        af[mf] = *(const short8*)((const char*)hs +
                    ((mf * 16 + fl) * 512 + ((ks * 64 + q * 16) ^ sw)));
#pragma unroll
      for (int mf = 0; mf < 4; ++mf) {
        yacc[mf][0] = __builtin_amdgcn_mfma_f32_16x16x32_bf16(af[mf], b0, yacc[mf][0], 0, 0, 0);
        yacc[mf][1] = __builtin_amdgcn_mfma_f32_16x16x32_bf16(af[mf], b1v, yacc[mf][1], 0, 0, 0);
      }
    }
  }

  if (USE_Y) {
    // Y store: bf16 row-pairs packed in u32, coalesced; odd-padding never read
    int ybase = 0;
#pragma unroll
    for (int ee = 0; ee < NE; ++ee) {
      int c2 = (cnt[ee * 64] + 1) & ~1;       // even-padded regions
      ybase += (ee < e) ? c2 : 0;
    }
#pragma unroll
    for (int mf = 0; mf < 4; ++mf)
#pragma unroll
      for (int jp = 0; jp < 2; ++jp) {
        int ml = mf * 16 + q * 4 + jp * 2;    // even local row
        if (m0 + ml < ce) {
          unsigned int* dst = ypair + (size_t)((ybase + m0 + ml) >> 1) * DM + wid * 32;
#pragma unroll
          for (int nf = 0; nf < 2; ++nf) {
            unsigned int pv = f2bf1(yacc[mf][nf][jp * 2]) |
                              (f2bf1(yacc[mf][nf][jp * 2 + 1]) << 16);
            dst[nf * 16 + fl] = pv;
          }
        }
      }
  } else {
    const float* wgtg = wgt + e * T_TOK + m0;
    float b2v[2];
    b2v[0] = b2[e * DM + wid * 32 + fl];
    b2v[1] = b2[e * DM + wid * 32 + 16 + fl];
#pragma unroll
    for (int mf = 0; mf < 4; ++mf)
#pragma unroll
      for (int j = 0; j < 4; ++j) {
        int ml = mf * 16 + q * 4 + j;
        if (m0 + ml < ce) {
          int tk = tokg[ml];
          float w = wgtg[ml];
          float* orow = out + (size_t)tk * DM + wid * 32;
#pragma unroll
          for (int nf = 0; nf < 2; ++nf)
            atomicAdd(orow + nf * 16 + fl, w * (yacc[mf][nf][j] + b2v[nf]));
        }
      }
  }
}

// out[t] = w0*(y[slot0]+b2[e0]) + w1*(y[slot1]+b2[e1])
__global__ __launch_bounds__(256) void combine_kernel(
    const unsigned int* __restrict__ ypair, const int* __restrict__ cnt,
    const int2* __restrict__ se2, const int2* __restrict__ sp2,
    const float2* __restrict__ sw2, const float* __restrict__ b2,
    float* __restrict__ out) {
  int tid = (int)threadIdx.x;
  int wid = tid >> 6, lane = tid & 63;
  int t = blockIdx.x * 4 + wid;
  int2 ee = se2[t]; int2 pp = sp2[t]; float2 w = sw2[t];
  int yb0 = 0, yb1 = 0;
#pragma unroll
  for (int k = 0; k < NE; ++k) {
    int c2 = (cnt[k * 64] + 1) & ~1;
    yb0 += (k < ee.x) ? c2 : 0;
    yb1 += (k < ee.y) ? c2 : 0;
  }
  int g0 = yb0 + pp.x, g1 = yb1 + pp.y;
  const unsigned int* y0 = ypair + (size_t)(g0 >> 1) * DM;
  const unsigned int* y1 = ypair + (size_t)(g1 >> 1) * DM;
  int h0 = (g0 & 1) << 4, h1 = (g1 & 1) << 4;
  const float* b20 = b2 + ee.x * DM;
  const float* b21 = b2 + ee.y * DM;
  float* orow = out + (size_t)t * DM;
#pragma unroll
  for (int i = 0; i < 2; ++i) {
    int c = lane * 8 + i * 4;
    uint4 a0 = *(const uint4*)(y0 + c);
    uint4 a1 = *(const uint4*)(y1 + c);
    f32x4 bb0 = *(const f32x4*)(b20 + c);
    f32x4 bb1 = *(const f32x4*)(b21 + c);
    f32x4 o;
    o.x = w.x * (bf2f((a0.x >> h0) & 0xffffu) + bb0.x) + w.y * (bf2f((a1.x >> h1) & 0xffffu) + bb1.x);
    o.y = w.x * (bf2f((a0.y >> h0) & 0xffffu) + bb0.y) + w.y * (bf2f((a1.y >> h1) & 0xffffu) + bb1.y);
    o.z = w.x * (bf2f((a0.z >> h0) & 0xffffu) + bb0.z) + w.y * (bf2f((a1.z >> h1) & 0xffffu) + bb1.z);
    o.w = w.x * (bf2f((a0.w >> h0) & 0xffffu) + bb0.w) + w.y * (bf2f((a1.w >> h1) & 0xffffu) + bb1.w);
    *(f32x4*)(orow + c) = o;
  }
}

extern "C" void kernel_launch(void* const* d_in, const int* in_sizes, int n_in,
                              void* d_out, int out_size, void* d_ws, size_t ws_size,
                              hipStream_t stream) {
  (void)in_sizes; (void)n_in; (void)out_size;
  const float* x  = (const float*)d_in[0];
  const float* gw = (const float*)d_in[1];
  const float* w1 = (const float*)d_in[2];
  const float* b1 = (const float*)d_in[3];
  const float* w2 = (const float*)d_in[4];
  const float* b2 = (const float*)d_in[5];
  float* out = (float*)d_out;

  char* ws = (char*)d_ws;
  size_t off = 0;
  auto alloc = [&](size_t sz) { char* p = ws + off; off += (sz + 255) & ~(size_t)255; return p; };
  int*   cnt = (int*)alloc(NE * 64 * 4);
  int*   tok = (int*)alloc((size_t)NE * T_TOK * 4);
  float* wgt = (float*)alloc((size_t)NE * T_TOK * 4);
  int2*  se2 = (int2*)alloc((size_t)T_TOK * 8);
  int2*  sp2 = (int2*)alloc((size_t)T_TOK * 8);
  float2* sw2 = (float2*)alloc((size_t)T_TOK * 8);
  unsigned int* xb = (unsigned int*)alloc((size_t)T_TOK * (DM / 2) * 4);
  unsigned short* w1t = (unsigned short*)alloc((size_t)NE * DFF * DM * 2);
  unsigned short* w2t = (unsigned short*)alloc((size_t)NE * DM * DFF * 2);
  unsigned int* ypair = (unsigned int*)alloc(((size_t)(2 * T_TOK + 2 * NE) / 2) * DM * 4);
  int use_y = (off <= ws_size) ? 1 : 0;

  hipMemsetAsync(cnt, 0, NE * 64 * 4, stream);
  if (!use_y) hipMemsetAsync(out, 0, (size_t)T_TOK * DM * 4, stream);

  tcvt_kernel<<<dim3(DFF / 32, DM / 32, NE), dim3(32, 8), 0, stream>>>(w1, w1t, DM, DFF);
  tcvt_kernel<<<dim3(DM / 32, DFF / 32, NE), dim3(32, 8), 0, stream>>>(w2, w2t, DFF, DM);
  gate_kernel<<<T_TOK / 16, 1024, 0, stream>>>(x, gw, cnt, tok, wgt, xb, se2, sp2, sw2);
  if (use_y) {
    ffn_kernel<1><<<NE * (T_TOK / BM), 1024, 0, stream>>>(xb, w1t, b1, w2t, b2, cnt, tok, wgt, ypair, out);
    combine_kernel<<<T_TOK / 4, 256, 0, stream>>>(ypair, cnt, se2, sp2, sw2, b2, out);
  } else {
    ffn_kernel<0><<<NE * (T_TOK / BM), 1024, 0, stream>>>(xb, w1t, b1, w2t, b2, cnt, tok, wgt, ypair, out);
  }
}

// Round 3
// 664.909 us; speedup vs baseline: 1.9570x; 1.2120x over previous
//
#include <hip/hip_runtime.h>
#include <math.h>

#define T_TOK 32768
#define DM 512
#define DFF 2048
#define NE 8
#define MAXTILES 528   // >= sum ceil(ce/128) worst case (65536/128 + 8)

typedef __attribute__((ext_vector_type(8))) short short8;
typedef __attribute__((ext_vector_type(4))) float f32x4;

__device__ __forceinline__ unsigned int f2bf1(float f) {
  union { float f; unsigned int u; } x; x.f = f;
  return (x.u + 0x7fffu + ((x.u >> 16) & 1u)) >> 16;  // RNE
}

// transpose + convert: src [E][R][C] f32 -> dst [E][C][R] bf16
__global__ void tcvt_kernel(const float* __restrict__ src, unsigned short* __restrict__ dst,
                            int R, int C) {
  __shared__ float tile[32][33];
  int e = blockIdx.z;
  const float* s = src + (size_t)e * R * C;
  unsigned short* d = dst + (size_t)e * R * C;
  int c0 = blockIdx.x * 32, r0 = blockIdx.y * 32;
  int tx = threadIdx.x, ty = threadIdx.y;
#pragma unroll
  for (int i = 0; i < 4; ++i)
    tile[ty + i * 8][tx] = s[(size_t)(r0 + ty + i * 8) * C + c0 + tx];
  __syncthreads();
#pragma unroll
  for (int i = 0; i < 4; ++i)
    d[(size_t)(c0 + ty + i * 8) * R + r0 + tx] = (unsigned short)f2bf1(tile[tx][ty + i * 8]);
}

// gating: 16 tokens per block (wave/token); emits x as bf16 + expert buckets
__global__ __launch_bounds__(1024) void gate_kernel(
    const float* __restrict__ x, const float* __restrict__ gw,
    int* __restrict__ cnt, int* __restrict__ tok, float* __restrict__ wgt,
    unsigned int* __restrict__ xb) {
  __shared__ int lcnt[NE];
  __shared__ int lbase[NE];
  __shared__ int wslot[16][2];
  __shared__ int winfo[16][2];
  __shared__ float wval[16][2];
  int tid = threadIdx.x;
  int wid = tid >> 6, lane = tid & 63;
  int t = blockIdx.x * 16 + wid;
  if (tid < NE) lcnt[tid] = 0;
  __syncthreads();

  float acc[NE];
#pragma unroll
  for (int e = 0; e < NE; ++e) acc[e] = 0.f;
  const float* xr = x + (size_t)t * DM;
  unsigned int* xbr = xb + (size_t)t * (DM / 2);
#pragma unroll
  for (int j = 0; j < 4; ++j) {
    int d0 = j * 128 + lane * 2;
    float2 xv = *(const float2*)(xr + d0);
    const float* g0 = gw + d0 * NE;
#pragma unroll
    for (int e = 0; e < NE; ++e) acc[e] += xv.x * g0[e] + xv.y * g0[NE + e];
    xbr[j * 64 + lane] = f2bf1(xv.x) | (f2bf1(xv.y) << 16);
  }
#pragma unroll
  for (int off = 32; off >= 1; off >>= 1) {
#pragma unroll
    for (int e = 0; e < NE; ++e) acc[e] += __shfl_xor(acc[e], off);
  }
  if (lane == 0) {
    int e0 = 0; float l0 = acc[0];
#pragma unroll
    for (int e = 1; e < NE; ++e) if (acc[e] > l0) { l0 = acc[e]; e0 = e; }
    int e1 = (e0 == 0) ? 1 : 0; float l1 = acc[e1];
#pragma unroll
    for (int e = 0; e < NE; ++e) if (e != e0 && acc[e] > l1) { l1 = acc[e]; e1 = e; }
    float w0 = 1.f / (1.f + expf(l1 - l0));   // renormalized top-2, exact
    winfo[wid][0] = e0; winfo[wid][1] = e1;
    wval[wid][0] = w0;  wval[wid][1] = 1.f - w0;
    wslot[wid][0] = atomicAdd(&lcnt[e0], 1);
    wslot[wid][1] = atomicAdd(&lcnt[e1], 1);
  }
  __syncthreads();
  if (tid < NE) lbase[tid] = atomicAdd(&cnt[tid * 64], lcnt[tid]);
  __syncthreads();
  if (lane == 0) {
    int e0 = winfo[wid][0], e1 = winfo[wid][1];
    int p0 = lbase[e0] + wslot[wid][0];
    int p1 = lbase[e1] + wslot[wid][1];
    tok[e0 * T_TOK + p0] = t; wgt[e0 * T_TOK + p0] = wval[wid][0];
    tok[e1 * T_TOK + p1] = t; wgt[e1 * T_TOK + p1] = wval[wid][1];
  }
}

// prefix over tiles: tile_base[e] = sum_{k<e} ceil(cnt[k]/128)
__global__ void plan_kernel(const int* __restrict__ cnt, int* __restrict__ tile_base) {
  if (threadIdx.x == 0 && blockIdx.x == 0) {
    int tb = 0;
    for (int e = 0; e < NE; ++e) { tile_base[e] = tb; tb += (cnt[e * 64] + 127) >> 7; }
    tile_base[NE] = tb;
  }
}

// GEMM1: H[slot][f] = gelu(gather(xb)[slot][k] @ w1t[f][k]^T + b1)   (128x128 tile, K=512)
__global__ __launch_bounds__(256) void gemm1_kernel(
    const unsigned int* __restrict__ xb, const unsigned short* __restrict__ w1t,
    const float* __restrict__ b1, const int* __restrict__ cnt,
    const int* __restrict__ tok, const int* __restrict__ tile_base,
    unsigned short* __restrict__ H, int tile_lo) {
  int bid = (int)blockIdx.x;
  int nt = bid & 15;
  int gt = tile_lo + (bid >> 4);
  if (gt >= tile_base[NE]) return;
  int e = 0;
#pragma unroll
  for (int k = 0; k < NE - 1; ++k) e += (gt >= tile_base[k + 1]) ? 1 : 0;
  int tloc = gt - tile_base[e];
  int ce = cnt[e * 64];
  int m0 = tloc * 128;
  int n0 = nt * 128;

  __shared__ unsigned short As[128 * 32];   // 8KB [row][32k], slot-swizzled
  __shared__ unsigned short Bs[128 * 32];   // 8KB

  int tid = (int)threadIdx.x;
  int lane = tid & 63;
  int wid = tid >> 6;
  int wm = wid & 1, wn = wid >> 1;
  int fl = lane & 15, q = lane >> 4;
  int sxy = ((q ^ ((fl >> 1) & 3)) << 4);

  const int* tokg = tok + e * T_TOK;
  int r0 = tid >> 2, r1 = 64 + (tid >> 2);
  int sl = tid & 3;
  int ss0 = sl ^ ((r0 >> 1) & 3);
  int ss1 = sl ^ ((r1 >> 1) & 3);
  int t0 = tokg[min(m0 + r0, ce - 1)];
  int t1 = tokg[min(m0 + r1, ce - 1)];
  const char* asrc0 = (const char*)xb + (size_t)t0 * 1024 + ss0 * 16;
  const char* asrc1 = (const char*)xb + (size_t)t1 * 1024 + ss1 * 16;
  const char* bsrc0 = (const char*)w1t + ((size_t)e * DFF + n0 + r0) * 1024 + ss0 * 16;
  const char* bsrc1 = (const char*)w1t + ((size_t)e * DFF + n0 + r1) * 1024 + ss1 * 16;
  char* adst0 = (char*)As + tid * 16;
  char* adst1 = (char*)As + 4096 + tid * 16;
  char* bdst0 = (char*)Bs + tid * 16;
  char* bdst1 = (char*)Bs + 4096 + tid * 16;

  int aoff[4], boff[4];
#pragma unroll
  for (int i = 0; i < 4; ++i) {
    aoff[i] = (wm * 64 + i * 16 + fl) * 64 + sxy;
    boff[i] = (wn * 64 + i * 16 + fl) * 64 + sxy;
  }

  f32x4 acc[4][4];
#pragma unroll
  for (int a = 0; a < 4; ++a)
#pragma unroll
    for (int b = 0; b < 4; ++b) acc[a][b] = (f32x4){0.f, 0.f, 0.f, 0.f};

  for (int t = 0; t < 16; ++t) {
    size_t ko = (size_t)t * 64;
    __builtin_amdgcn_global_load_lds((const __attribute__((address_space(1))) unsigned int*)(asrc0 + ko),
                                     (__attribute__((address_space(3))) unsigned int*)adst0, 16, 0, 0);
    __builtin_amdgcn_global_load_lds((const __attribute__((address_space(1))) unsigned int*)(asrc1 + ko),
                                     (__attribute__((address_space(3))) unsigned int*)adst1, 16, 0, 0);
    __builtin_amdgcn_global_load_lds((const __attribute__((address_space(1))) unsigned int*)(bsrc0 + ko),
                                     (__attribute__((address_space(3))) unsigned int*)bdst0, 16, 0, 0);
    __builtin_amdgcn_global_load_lds((const __attribute__((address_space(1))) unsigned int*)(bsrc1 + ko),
                                     (__attribute__((address_space(3))) unsigned int*)bdst1, 16, 0, 0);
    __syncthreads();
    short8 a[4], b[4];
#pragma unroll
    for (int i = 0; i < 4; ++i) {
      a[i] = *(const short8*)((const char*)As + aoff[i]);
      b[i] = *(const short8*)((const char*)Bs + boff[i]);
    }
#pragma unroll
    for (int mf = 0; mf < 4; ++mf)
#pragma unroll
      for (int nf = 0; nf < 4; ++nf)
        acc[mf][nf] = __builtin_amdgcn_mfma_f32_16x16x32_bf16(a[mf], b[nf], acc[mf][nf], 0, 0, 0);
    __syncthreads();
  }

  size_t hrow0 = (size_t)(gt - tile_lo) * 128;
#pragma unroll
  for (int nf = 0; nf < 4; ++nf) {
    float bias = b1[e * DFF + n0 + wn * 64 + nf * 16 + fl];
    int col = n0 + wn * 64 + nf * 16 + fl;
#pragma unroll
    for (int mf = 0; mf < 4; ++mf)
#pragma unroll
      for (int j = 0; j < 4; ++j) {
        int row = wm * 64 + mf * 16 + q * 4 + j;
        float v = acc[mf][nf][j] + bias;
        v = 0.5f * v * (1.f + erff(v * 0.70710678118654752f));
        H[(hrow0 + row) * DFF + col] = (unsigned short)f2bf1(v);
      }
  }
}

// GEMM2: out[tok[slot]] += wgt[slot]*(H[slot][k] @ w2t[n][k]^T + b2[n])   (K=2048)
__global__ __launch_bounds__(256) void gemm2_kernel(
    const unsigned short* __restrict__ H, const unsigned short* __restrict__ w2t,
    const float* __restrict__ b2, const int* __restrict__ cnt,
    const int* __restrict__ tok, const float* __restrict__ wgt,
    const int* __restrict__ tile_base, float* __restrict__ out, int tile_lo) {
  int bid = (int)blockIdx.x;
  int nt = bid & 3;
  int gt = tile_lo + (bid >> 2);
  if (gt >= tile_base[NE]) return;
  int e = 0;
#pragma unroll
  for (int k = 0; k < NE - 1; ++k) e += (gt >= tile_base[k + 1]) ? 1 : 0;
  int tloc = gt - tile_base[e];
  int ce = cnt[e * 64];
  int m0 = tloc * 128;
  int n0 = nt * 128;

  __shared__ unsigned short As[128 * 32];
  __shared__ unsigned short Bs[128 * 32];

  int tid = (int)threadIdx.x;
  int lane = tid & 63;
  int wid = tid >> 6;
  int wm = wid & 1, wn = wid >> 1;
  int fl = lane & 15, q = lane >> 4;
  int sxy = ((q ^ ((fl >> 1) & 3)) << 4);

  int r0 = tid >> 2, r1 = 64 + (tid >> 2);
  int sl = tid & 3;
  int ss0 = sl ^ ((r0 >> 1) & 3);
  int ss1 = sl ^ ((r1 >> 1) & 3);
  size_t hrow0 = (size_t)(gt - tile_lo) * 128;
  const char* asrc0 = (const char*)H + (hrow0 + r0) * 4096 + ss0 * 16;
  const char* asrc1 = (const char*)H + (hrow0 + r1) * 4096 + ss1 * 16;
  const char* bsrc0 = (const char*)w2t + ((size_t)e * DM + n0 + r0) * 4096 + ss0 * 16;
  const char* bsrc1 = (const char*)w2t + ((size_t)e * DM + n0 + r1) * 4096 + ss1 * 16;
  char* adst0 = (char*)As + tid * 16;
  char* adst1 = (char*)As + 4096 + tid * 16;
  char* bdst0 = (char*)Bs + tid * 16;
  char* bdst1 = (char*)Bs + 4096 + tid * 16;

  int aoff[4], boff[4];
#pragma unroll
  for (int i = 0; i < 4; ++i) {
    aoff[i] = (wm * 64 + i * 16 + fl) * 64 + sxy;
    boff[i] = (wn * 64 + i * 16 + fl) * 64 + sxy;
  }

  f32x4 acc[4][4];
#pragma unroll
  for (int a = 0; a < 4; ++a)
#pragma unroll
    for (int b = 0; b < 4; ++b) acc[a][b] = (f32x4){0.f, 0.f, 0.f, 0.f};

  for (int t = 0; t < 64; ++t) {
    size_t ko = (size_t)t * 64;
    __builtin_amdgcn_global_load_lds((const __attribute__((address_space(1))) unsigned int*)(asrc0 + ko),
                                     (__attribute__((address_space(3))) unsigned int*)adst0, 16, 0, 0);
    __builtin_amdgcn_global_load_lds((const __attribute__((address_space(1))) unsigned int*)(asrc1 + ko),
                                     (__attribute__((address_space(3))) unsigned int*)adst1, 16, 0, 0);
    __builtin_amdgcn_global_load_lds((const __attribute__((address_space(1))) unsigned int*)(bsrc0 + ko),
                                     (__attribute__((address_space(3))) unsigned int*)bdst0, 16, 0, 0);
    __builtin_amdgcn_global_load_lds((const __attribute__((address_space(1))) unsigned int*)(bsrc1 + ko),
                                     (__attribute__((address_space(3))) unsigned int*)bdst1, 16, 0, 0);
    __syncthreads();
    short8 a[4], b[4];
#pragma unroll
    for (int i = 0; i < 4; ++i) {
      a[i] = *(const short8*)((const char*)As + aoff[i]);
      b[i] = *(const short8*)((const char*)Bs + boff[i]);
    }
#pragma unroll
    for (int mf = 0; mf < 4; ++mf)
#pragma unroll
      for (int nf = 0; nf < 4; ++nf)
        acc[mf][nf] = __builtin_amdgcn_mfma_f32_16x16x32_bf16(a[mf], b[nf], acc[mf][nf], 0, 0, 0);
    __syncthreads();
  }

  const int* tokg = tok + e * T_TOK;
  const float* wgtg = wgt + e * T_TOK;
  float bias2[4];
#pragma unroll
  for (int nf = 0; nf < 4; ++nf) bias2[nf] = b2[e * DM + n0 + wn * 64 + nf * 16 + fl];
#pragma unroll
  for (int mf = 0; mf < 4; ++mf)
#pragma unroll
    for (int j = 0; j < 4; ++j) {
      int row = wm * 64 + mf * 16 + q * 4 + j;
      int slot = m0 + row;
      if (slot < ce) {
        int tk = tokg[slot];
        float w = wgtg[slot];
        float* orow = out + (size_t)tk * DM + n0 + wn * 64;
#pragma unroll
        for (int nf = 0; nf < 4; ++nf)
          atomicAdd(orow + nf * 16 + fl, w * (acc[mf][nf][j] + bias2[nf]));
      }
    }
}

extern "C" void kernel_launch(void* const* d_in, const int* in_sizes, int n_in,
                              void* d_out, int out_size, void* d_ws, size_t ws_size,
                              hipStream_t stream) {
  (void)in_sizes; (void)n_in; (void)out_size;
  const float* x  = (const float*)d_in[0];
  const float* gw = (const float*)d_in[1];
  const float* w1 = (const float*)d_in[2];
  const float* b1 = (const float*)d_in[3];
  const float* w2 = (const float*)d_in[4];
  const float* b2 = (const float*)d_in[5];
  float* out = (float*)d_out;

  char* ws = (char*)d_ws;
  size_t off = 0;
  auto alloc = [&](size_t sz) { char* p = ws + off; off += (sz + 255) & ~(size_t)255; return p; };
  int*   cnt = (int*)alloc(NE * 64 * 4);
  int*   tok = (int*)alloc((size_t)NE * T_TOK * 4);
  float* wgt = (float*)alloc((size_t)NE * T_TOK * 4);
  int*   tile_base = (int*)alloc((NE + 1) * 4);
  unsigned int* xb = (unsigned int*)alloc((size_t)T_TOK * (DM / 2) * 4);
  unsigned short* w1t = (unsigned short*)alloc((size_t)NE * DFF * DM * 2);
  unsigned short* w2t = (unsigned short*)alloc((size_t)NE * DM * DFF * 2);

  // H chunking to fit ws
  size_t avail = (ws_size > off) ? (ws_size - off) : 0;
  int TPC = MAXTILES, NC = 1;
  while (NC < 32 && (size_t)TPC * 128 * DFF * 2 > avail) {
    NC *= 2; TPC = (MAXTILES + NC - 1) / NC;
  }
  unsigned short* H = (unsigned short*)alloc((size_t)TPC * 128 * DFF * 2);

  hipMemsetAsync(cnt, 0, NE * 64 * 4, stream);
  hipMemsetAsync(out, 0, (size_t)T_TOK * DM * 4, stream);

  tcvt_kernel<<<dim3(DFF / 32, DM / 32, NE), dim3(32, 8), 0, stream>>>(w1, w1t, DM, DFF);
  tcvt_kernel<<<dim3(DM / 32, DFF / 32, NE), dim3(32, 8), 0, stream>>>(w2, w2t, DFF, DM);
  gate_kernel<<<T_TOK / 16, 1024, 0, stream>>>(x, gw, cnt, tok, wgt, xb);
  plan_kernel<<<1, 64, 0, stream>>>(cnt, tile_base);

  for (int c = 0; c < NC; ++c) {
    int lo = c * TPC;
    if (lo >= MAXTILES) break;
    gemm1_kernel<<<TPC * 16, 256, 0, stream>>>(xb, w1t, b1, cnt, tok, tile_base, H, lo);
    gemm2_kernel<<<TPC * 4, 256, 0, stream>>>(H, w2t, b2, cnt, tok, wgt, tile_base, out, lo);
  }
}